// Round 1
// baseline (321.980 us; speedup 1.0000x reference)
//
#include <hip/hip_runtime.h>
#include <math.h>

#define DIM 128

// ---------------- Kernel 1: build the 128x128 layer unitary ----------------
// Block j simulates column j (state = e_j) through 5 StronglyEntanglingLayers.
// Packed output layout (for kernel2 coalescing):
//   row i occupies floats [i*256, i*256+256): first 128 = Re, next 128 = Im,
//   element (i, j) with j = q*32 + k*4 + e stored at offset (k*4+q)*4 + e.
__global__ __launch_bounds__(128) void build_unitary_k(
    const float* __restrict__ qw, float* __restrict__ Up) {
  __shared__ float sre[DIM], sim_[DIM];
  __shared__ float gm[35][8];  // U00r,U00i,U01r,U01i,U10r,U10i,U11r,U11i
  const int tid = threadIdx.x;
  const int col = blockIdx.x;

  if (tid < 35) {
    // Rot(phi, theta, omega) = RZ(omega) RY(theta) RZ(phi)
    const float phi = qw[tid * 3 + 0];
    const float th  = qw[tid * 3 + 1];
    const float om  = qw[tid * 3 + 2];
    float sh, ch; sincosf(0.5f * th, &sh, &ch);
    const float a = 0.5f * (phi + om);
    const float b = 0.5f * (phi - om);
    float sa, ca; sincosf(a, &sa, &ca);
    float sb, cb; sincosf(b, &sb, &cb);
    gm[tid][0] =  ca * ch;  gm[tid][1] = -sa * ch;   // U00 = e^{-ia} c
    gm[tid][2] = -cb * sh;  gm[tid][3] = -sb * sh;   // U01 = -e^{+ib} s
    gm[tid][4] =  cb * sh;  gm[tid][5] = -sb * sh;   // U10 = e^{-ib} s
    gm[tid][6] =  ca * ch;  gm[tid][7] =  sa * ch;   // U11 = e^{+ia} c
  }
  sre[tid]  = (tid == col) ? 1.0f : 0.0f;
  sim_[tid] = 0.0f;
  __syncthreads();

  for (int l = 0; l < 5; ++l) {
    const int r = l % 6 + 1;
    // Rot on each wire q (wire 0 = MSB: bit (6-q))
    for (int q = 0; q < 7; ++q) {
      const int shft = 6 - q;
      const int bit = (tid >> shft) & 1;
      const int p = tid ^ (1 << shft);
      const float* g = gm[l * 7 + q];
      const float ar = sre[tid], ai = sim_[tid];
      const float br = sre[p],   bi = sim_[p];
      const float udr = bit ? g[6] : g[0], udi = bit ? g[7] : g[1];
      const float uor = bit ? g[4] : g[2], uoi = bit ? g[5] : g[3];
      const float nr = udr * ar - udi * ai + uor * br - uoi * bi;
      const float ni = udr * ai + udi * ar + uor * bi + uoi * br;
      __syncthreads();
      sre[tid] = nr; sim_[tid] = ni;
      __syncthreads();
    }
    // ring of CNOTs: control q, target (q+r)%7
    for (int q = 0; q < 7; ++q) {
      const int tg = (q + r) % 7;
      const int mc = 1 << (6 - q), mt = 1 << (6 - tg);
      const int src = (tid & mc) ? (tid ^ mt) : tid;
      const float nr = sre[src], ni = sim_[src];
      __syncthreads();
      sre[tid] = nr; sim_[tid] = ni;
      __syncthreads();
    }
  }
  // scatter into packed layout
  const int q4 = col >> 5, k4 = (col >> 2) & 7, e4 = col & 3;
  const int pos = (k4 * 4 + q4) * 4 + e4;
  Up[tid * 256 + pos]       = sre[tid];
  Up[tid * 256 + 128 + pos] = sim_[tid];
}

// ---------------- Kernel 2: per-sample y = U s, expvals, MLP ----------------
// 4 threads (a "quad") per sample; quad member owns j-slice [quad*32, quad*32+32).
__global__ __launch_bounds__(256) void vqc_mlp_k(
    const float* __restrict__ x, const float* __restrict__ Up,
    const float* __restrict__ W1, const float* __restrict__ b1,
    const float* __restrict__ W2, const float* __restrict__ b2,
    float* __restrict__ out) {
  const int t = blockIdx.x * 256 + threadIdx.x;
  const int sid = t >> 2;
  const int quad = t & 3;

  // embedding angles
  float cq[7], sq[7];
  #pragma unroll
  for (int q = 0; q < 7; ++q) {
    const float xv = 0.5f * x[sid * 7 + q];
    sincosf(xv, &sq[q], &cq[q]);
  }
  // product-state slice: j = quad*32 + jj ; quad bit1 = wire0, bit0 = wire1;
  // jj bits 4..0 = wires 2..6
  float sv[32];
  sv[0] = ((quad & 2) ? sq[0] : cq[0]) * ((quad & 1) ? sq[1] : cq[1]);
  #pragma unroll
  for (int q = 2; q < 7; ++q) {
    const int cnt = 1 << (q - 2);
    #pragma unroll
    for (int tt = cnt - 1; tt >= 0; --tt) {
      const float v = sv[tt];
      sv[2 * tt + 1] = v * sq[q];
      sv[2 * tt]     = v * cq[q];
    }
  }

  float qa[7] = {0.f, 0.f, 0.f, 0.f, 0.f, 0.f, 0.f};
  const float4* __restrict__ U4 = (const float4*)Up;
  for (int i = 0; i < 128; ++i) {
    const float4* __restrict__ row = U4 + i * 64;  // 64 float4 per row
    float pr = 0.f, pi = 0.f;
    #pragma unroll
    for (int k = 0; k < 8; ++k) {
      const float4 ur = row[k * 4 + quad];        // Re chunk
      const float4 ui = row[32 + k * 4 + quad];   // Im chunk
      pr += ur.x * sv[k * 4 + 0]; pr += ur.y * sv[k * 4 + 1];
      pr += ur.z * sv[k * 4 + 2]; pr += ur.w * sv[k * 4 + 3];
      pi += ui.x * sv[k * 4 + 0]; pi += ui.y * sv[k * 4 + 1];
      pi += ui.z * sv[k * 4 + 2]; pi += ui.w * sv[k * 4 + 3];
    }
    // assemble full y_i across the quad (lanes differing in bits 0,1)
    pr += __shfl_xor(pr, 1); pr += __shfl_xor(pr, 2);
    pi += __shfl_xor(pi, 1); pi += __shfl_xor(pi, 2);
    const float p = pr * pr + pi * pi;
    #pragma unroll
    for (int w = 0; w < 7; ++w)
      qa[w] += ((i >> (6 - w)) & 1) ? -p : p;
  }

  // MLP: h = relu(W1 qa + b1); logits = W2 h + b2 (quad splits the 22 outputs)
  float h[16];
  #pragma unroll
  for (int k = 0; k < 16; ++k) {
    float acc = b1[k];
    #pragma unroll
    for (int q = 0; q < 7; ++q) acc += W1[k * 7 + q] * qa[q];
    h[k] = fmaxf(acc, 0.f);
  }
  for (int o = quad; o < 22; o += 4) {
    float acc = b2[o];
    #pragma unroll
    for (int k = 0; k < 16; ++k) acc += W2[o * 16 + k] * h[k];
    out[sid * 22 + o] = acc;
  }
}

extern "C" void kernel_launch(void* const* d_in, const int* in_sizes, int n_in,
                              void* d_out, int out_size, void* d_ws, size_t ws_size,
                              hipStream_t stream) {
  const float* x  = (const float*)d_in[0];
  const float* qw = (const float*)d_in[1];
  const float* W1 = (const float*)d_in[2];
  const float* b1 = (const float*)d_in[3];
  const float* W2 = (const float*)d_in[4];
  const float* b2 = (const float*)d_in[5];
  float* out = (float*)d_out;
  float* Up  = (float*)d_ws;  // 128*256*4 = 128 KiB scratch

  const int B = in_sizes[0] / 7;

  build_unitary_k<<<DIM, DIM, 0, stream>>>(qw, Up);

  const int threads = B * 4;
  vqc_mlp_k<<<(threads + 255) / 256, 256, 0, stream>>>(x, Up, W1, b1, W2, b2, out);
}

// Round 2
// 115.085 us; speedup vs baseline: 2.7978x; 2.7978x over previous
//
#include <hip/hip_runtime.h>
#include <math.h>

#define DIM 128
#define MBLK 64      // samples per block
#define SPAD 132     // padded LDS row (floats) -- breaks write-phase bank conflicts

// ---------------- Kernel 1: build the 128x128 layer unitary ----------------
// Block k simulates column k (state = e_k) through 5 StronglyEntanglingLayers.
// k-major packed output: Upk[k*256 + i] = Re U[i][k], Upk[k*256 + 128 + i] = Im U[i][k]
__global__ __launch_bounds__(128) void build_unitary_k(
    const float* __restrict__ qw, float* __restrict__ Up) {
  __shared__ float sre[DIM], sim_[DIM];
  __shared__ float gm[35][8];  // U00r,U00i,U01r,U01i,U10r,U10i,U11r,U11i
  const int tid = threadIdx.x;
  const int col = blockIdx.x;

  if (tid < 35) {
    // Rot(phi, theta, omega) = RZ(omega) RY(theta) RZ(phi)
    const float phi = qw[tid * 3 + 0];
    const float th  = qw[tid * 3 + 1];
    const float om  = qw[tid * 3 + 2];
    float sh, ch; sincosf(0.5f * th, &sh, &ch);
    const float a = 0.5f * (phi + om);
    const float b = 0.5f * (phi - om);
    float sa, ca; sincosf(a, &sa, &ca);
    float sb, cb; sincosf(b, &sb, &cb);
    gm[tid][0] =  ca * ch;  gm[tid][1] = -sa * ch;   // U00 = e^{-ia} c
    gm[tid][2] = -cb * sh;  gm[tid][3] = -sb * sh;   // U01 = -e^{+ib} s
    gm[tid][4] =  cb * sh;  gm[tid][5] = -sb * sh;   // U10 = e^{-ib} s
    gm[tid][6] =  ca * ch;  gm[tid][7] =  sa * ch;   // U11 = e^{+ia} c
  }
  sre[tid]  = (tid == col) ? 1.0f : 0.0f;
  sim_[tid] = 0.0f;
  __syncthreads();

  for (int l = 0; l < 5; ++l) {
    const int r = l % 6 + 1;
    for (int q = 0; q < 7; ++q) {
      const int shft = 6 - q;
      const int bit = (tid >> shft) & 1;
      const int p = tid ^ (1 << shft);
      const float* g = gm[l * 7 + q];
      const float ar = sre[tid], ai = sim_[tid];
      const float br = sre[p],   bi = sim_[p];
      const float udr = bit ? g[6] : g[0], udi = bit ? g[7] : g[1];
      const float uor = bit ? g[4] : g[2], uoi = bit ? g[5] : g[3];
      const float nr = udr * ar - udi * ai + uor * br - uoi * bi;
      const float ni = udr * ai + udi * ar + uor * bi + uoi * br;
      __syncthreads();
      sre[tid] = nr; sim_[tid] = ni;
      __syncthreads();
    }
    for (int q = 0; q < 7; ++q) {
      const int tg = (q + r) % 7;
      const int mc = 1 << (6 - q), mt = 1 << (6 - tg);
      const int src = (tid & mc) ? (tid ^ mt) : tid;
      const float nr = sre[src], ni = sim_[src];
      __syncthreads();
      sre[tid] = nr; sim_[tid] = ni;
      __syncthreads();
    }
  }
  Up[col * 256 + tid]       = sre[tid];
  Up[col * 256 + 128 + tid] = sim_[tid];
}

// ---------------- Kernel 2: register-blocked f32 GEMM + expvals + MLP ------
// Block: 512 threads = 16 rows x 32 cols. Block tile: 64 samples x 128 i.
// Thread tile: 4 samples (row*4..+3) x 4 i (col*4..+3) x {re,im}.
#define FMA4(A, U, Sx) { A.x += U.x * Sx; A.y += U.y * Sx; A.z += U.z * Sx; A.w += U.w * Sx; }

__global__ __launch_bounds__(512) void vqc_mlp_k(
    const float* __restrict__ x, const float* __restrict__ Up,
    const float* __restrict__ W1, const float* __restrict__ b1,
    const float* __restrict__ W2, const float* __restrict__ b2,
    float* __restrict__ out) {
  __shared__ float S[MBLK * SPAD];
  const int tid = threadIdx.x;
  const int s0 = blockIdx.x * MBLK;

  // ---- phase 1: build product-state tile S[sample][k] (8 threads/sample) ----
  {
    const int sam = tid >> 3;   // 0..63
    const int oct = tid & 7;    // owns k = oct*16 .. oct*16+15
    const int gs = s0 + sam;
    float cq[7], sq[7];
    #pragma unroll
    for (int q = 0; q < 7; ++q) {
      const float xv = 0.5f * x[gs * 7 + q];
      sincosf(xv, &sq[q], &cq[q]);
    }
    // k bits: b0..b6 (wire0 = MSB). oct = b0b1b2, low 4 bits = wires 3..6
    float sv[16];
    sv[0] = ((oct & 4) ? sq[0] : cq[0]) * ((oct & 2) ? sq[1] : cq[1]) *
            ((oct & 1) ? sq[2] : cq[2]);
    #pragma unroll
    for (int q = 3; q < 7; ++q) {
      const int cnt = 1 << (q - 3);
      #pragma unroll
      for (int t = cnt - 1; t >= 0; --t) {
        const float v = sv[t];
        sv[2 * t + 1] = v * sq[q];
        sv[2 * t]     = v * cq[q];
      }
    }
    float* dst = &S[sam * SPAD + oct * 16];
    #pragma unroll
    for (int j4 = 0; j4 < 4; ++j4)
      *(float4*)(dst + j4 * 4) =
          make_float4(sv[4 * j4], sv[4 * j4 + 1], sv[4 * j4 + 2], sv[4 * j4 + 3]);
  }
  __syncthreads();

  // ---- phase 2: Y[sample][i] = sum_k S[sample][k] * U[i][k] ----
  const int col = tid & 31;   // i = col*4 .. col*4+3
  const int row = tid >> 5;   // samples row*4 .. row*4+3
  float4 ar[4], ai[4];
  #pragma unroll
  for (int t = 0; t < 4; ++t) {
    ar[t] = make_float4(0.f, 0.f, 0.f, 0.f);
    ai[t] = make_float4(0.f, 0.f, 0.f, 0.f);
  }
  const float* Sb = &S[(row * 4) * SPAD];
  const float4* __restrict__ Uq = (const float4*)Up + col;

  for (int k4 = 0; k4 < 32; ++k4) {
    float4 su[4];
    #pragma unroll
    for (int t = 0; t < 4; ++t)
      su[t] = *(const float4*)(Sb + t * SPAD + k4 * 4);
    #pragma unroll
    for (int e = 0; e < 4; ++e) {
      const float4 ur = Uq[(k4 * 4 + e) * 64];
      const float4 ui = Uq[(k4 * 4 + e) * 64 + 32];
      #pragma unroll
      for (int t = 0; t < 4; ++t) {
        const float sx = (&su[t].x)[e];
        FMA4(ar[t], ur, sx);
        FMA4(ai[t], ui, sx);
      }
    }
  }

  // ---- phase 3: probs, sign-fold to 7 expvals, reduce over 32 cols ----
  float qa[4][7];
  #pragma unroll
  for (int t = 0; t < 4; ++t) {
    float p0 = ar[t].x * ar[t].x + ai[t].x * ai[t].x;
    float p1 = ar[t].y * ar[t].y + ai[t].y * ai[t].y;
    float p2 = ar[t].z * ar[t].z + ai[t].z * ai[t].z;
    float p3 = ar[t].w * ar[t].w + ai[t].w * ai[t].w;
    const float ps = p0 + p1 + p2 + p3;
    #pragma unroll
    for (int w = 0; w < 5; ++w)   // i bits 6..2 == col bits 4..0
      qa[t][w] = ((col >> (4 - w)) & 1) ? -ps : ps;
    qa[t][5] = p0 + p1 - p2 - p3; // i bit 1 == e bit 1
    qa[t][6] = p0 - p1 + p2 - p3; // i bit 0 == e bit 0
  }
  #pragma unroll
  for (int m = 1; m <= 16; m <<= 1) {
    #pragma unroll
    for (int t = 0; t < 4; ++t)
      #pragma unroll
      for (int w = 0; w < 7; ++w)
        qa[t][w] += __shfl_xor(qa[t][w], m);
  }

  // ---- phase 4: MLP; column o (<22) computes logit o for its 4 samples ----
  if (col < 22) {
    #pragma unroll
    for (int t = 0; t < 4; ++t) {
      float h[16];
      #pragma unroll
      for (int k = 0; k < 16; ++k) {
        float acc = b1[k];
        #pragma unroll
        for (int q = 0; q < 7; ++q) acc += W1[k * 7 + q] * qa[t][q];
        h[k] = fmaxf(acc, 0.f);
      }
      float lg = b2[col];
      #pragma unroll
      for (int k = 0; k < 16; ++k) lg += W2[col * 16 + k] * h[k];
      out[(s0 + row * 4 + t) * 22 + col] = lg;
    }
  }
}

extern "C" void kernel_launch(void* const* d_in, const int* in_sizes, int n_in,
                              void* d_out, int out_size, void* d_ws, size_t ws_size,
                              hipStream_t stream) {
  const float* x  = (const float*)d_in[0];
  const float* qw = (const float*)d_in[1];
  const float* W1 = (const float*)d_in[2];
  const float* b1 = (const float*)d_in[3];
  const float* W2 = (const float*)d_in[4];
  const float* b2 = (const float*)d_in[5];
  float* out = (float*)d_out;
  float* Up  = (float*)d_ws;  // 128*256*4 = 128 KiB scratch

  const int B = in_sizes[0] / 7;

  build_unitary_k<<<DIM, DIM, 0, stream>>>(qw, Up);

  const int blocks = (B + MBLK - 1) / MBLK;
  vqc_mlp_k<<<blocks, 512, 0, stream>>>(x, Up, W1, b1, W2, b2, out);
}

// Round 4
// 109.529 us; speedup vs baseline: 2.9397x; 1.0507x over previous
//
#include <hip/hip_runtime.h>
#include <math.h>

#define DIM 128
#define MBLK 64      // samples per block (kernel2)
#define SPAD 132     // padded LDS row (floats), 16B-aligned stride
#define CHUNK 8      // k-values staged per LDS chunk (kernel2)

// ---------------- Kernel 1: build the 128x128 layer unitary ----------------
// One WAVE per column (no barriers in the gate loop). Lane l holds amplitudes
// i = l (lo) and i = l + 64 (hi); bit 6 of the index = wire 0.
// k-major packed output: Up[k*256 + i] = Re U[i][k], Up[k*256 + 128 + i] = Im U[i][k]
__global__ __launch_bounds__(256) void build_unitary_k(
    const float* __restrict__ qw, float* __restrict__ Up) {
  __shared__ float gm[35][8];  // U00r,U00i,U01r,U01i,U10r,U10i,U11r,U11i
  const int tid = threadIdx.x;

  if (tid < 35) {
    // Rot(phi, theta, omega) = RZ(omega) RY(theta) RZ(phi)
    const float phi = qw[tid * 3 + 0];
    const float th  = qw[tid * 3 + 1];
    const float om  = qw[tid * 3 + 2];
    float sh, ch; sincosf(0.5f * th, &sh, &ch);
    const float a = 0.5f * (phi + om);
    const float b = 0.5f * (phi - om);
    float sa, ca; sincosf(a, &sa, &ca);
    float sb, cb; sincosf(b, &sb, &cb);
    gm[tid][0] =  ca * ch;  gm[tid][1] = -sa * ch;   // U00 = e^{-ia} c
    gm[tid][2] = -cb * sh;  gm[tid][3] = -sb * sh;   // U01 = -e^{+ib} s
    gm[tid][4] =  cb * sh;  gm[tid][5] = -sb * sh;   // U10 = e^{-ib} s
    gm[tid][6] =  ca * ch;  gm[tid][7] =  sa * ch;   // U11 = e^{+ia} c
  }
  __syncthreads();

  const int lane = tid & 63;
  const int col  = blockIdx.x * 4 + (tid >> 6);

  float rl = (col == lane)      ? 1.f : 0.f;
  float rh = (col == lane + 64) ? 1.f : 0.f;
  float il = 0.f, ih = 0.f;

  for (int l = 0; l < 5; ++l) {
    const int r = l % 6 + 1;
    // --- Rot on each wire q (wire q = index bit 6-q) ---
    for (int q = 0; q < 7; ++q) {
      const float* g = gm[l * 7 + q];
      const float g0 = g[0], g1 = g[1], g2 = g[2], g3 = g[3];
      const float g4 = g[4], g5 = g[5], g6 = g[6], g7 = g[7];
      if (q == 0) {  // pair (lo,hi) lives in-lane
        const float nrl = g0 * rl - g1 * il + g2 * rh - g3 * ih;
        const float nil = g0 * il + g1 * rl + g2 * ih + g3 * rh;
        const float nrh = g4 * rl - g5 * il + g6 * rh - g7 * ih;
        const float nih = g4 * il + g5 * rl + g6 * ih + g7 * rh;
        rl = nrl; il = nil; rh = nrh; ih = nih;
      } else {
        const int m = 1 << (6 - q);
        const int bit = (lane & m) ? 1 : 0;
        const float prl = __shfl_xor(rl, m), pil = __shfl_xor(il, m);
        const float prh = __shfl_xor(rh, m), pih = __shfl_xor(ih, m);
        const float udr = bit ? g6 : g0, udi = bit ? g7 : g1;
        const float uor = bit ? g4 : g2, uoi = bit ? g5 : g3;
        const float nrl = udr * rl - udi * il + uor * prl - uoi * pil;
        const float nil = udr * il + udi * rl + uor * pil + uoi * prl;
        const float nrh = udr * rh - udi * ih + uor * prh - uoi * pih;
        const float nih = udr * ih + udi * rh + uor * pih + uoi * prh;
        rl = nrl; il = nil; rh = nrh; ih = nih;
      }
    }
    // --- ring of CNOTs: control q, target (q+r)%7; new[i]=old[i^mt if cbit] ---
    for (int q = 0; q < 7; ++q) {
      const int tg = (q + r) % 7;
      if (q == 0) {            // control = bit 6: hi half permutes, lo unchanged
        const int mt = 1 << (6 - tg);
        const float prh = __shfl_xor(rh, mt), pih = __shfl_xor(ih, mt);
        rh = prh; ih = pih;
      } else if (tg == 0) {    // target = bit 6: swap lo<->hi where control set
        const int mc = 1 << (6 - q);
        const bool cb = (lane & mc) != 0;
        const float trl = cb ? rh : rl, til = cb ? ih : il;
        const float trh = cb ? rl : rh, tih = cb ? il : ih;
        rl = trl; il = til; rh = trh; ih = tih;
      } else {
        const int mc = 1 << (6 - q), mt = 1 << (6 - tg);
        const bool cb = (lane & mc) != 0;
        const float prl = __shfl_xor(rl, mt), pil = __shfl_xor(il, mt);
        const float prh = __shfl_xor(rh, mt), pih = __shfl_xor(ih, mt);
        rl = cb ? prl : rl; il = cb ? pil : il;
        rh = cb ? prh : rh; ih = cb ? pih : ih;
      }
    }
  }
  float* dst = Up + col * 256;
  dst[lane]       = rl;  dst[64 + lane]  = rh;
  dst[128 + lane] = il;  dst[192 + lane] = ih;
}

// ---------------- Kernel 2: LDS-staged f32 GEMM + expvals + MLP ------------
// Block: 512 threads = 16 rows x 32 cols; tile 64 samples x 128 i.
// Thread tile: 4 samples x 4 i x {re,im}. U streamed through LDS double-buffer.
#define FMA4(A, U, Sx) { A.x += U.x * Sx; A.y += U.y * Sx; A.z += U.z * Sx; A.w += U.w * Sx; }

__global__ __launch_bounds__(512) void vqc_mlp_k(
    const float* __restrict__ x, const float* __restrict__ Up,
    const float* __restrict__ W1, const float* __restrict__ b1,
    const float* __restrict__ W2, const float* __restrict__ b2,
    float* __restrict__ out) {
  __shared__ float S[MBLK * SPAD];          // 33.8 KB
  __shared__ float Ub[2][CHUNK * 256];      // 16 KB
  const int tid = threadIdx.x;
  const int s0 = blockIdx.x * MBLK;

  // ---- phase 1: product-state tile S[sample][k] (8 threads/sample) ----
  {
    const int sam = tid >> 3;
    const int oct = tid & 7;
    const int gs = s0 + sam;
    float cq[7], sq[7];
    #pragma unroll
    for (int q = 0; q < 7; ++q) {
      const float xv = 0.5f * x[gs * 7 + q];
      sincosf(xv, &sq[q], &cq[q]);
    }
    float sv[16];
    sv[0] = ((oct & 4) ? sq[0] : cq[0]) * ((oct & 2) ? sq[1] : cq[1]) *
            ((oct & 1) ? sq[2] : cq[2]);
    #pragma unroll
    for (int q = 3; q < 7; ++q) {
      const int cnt = 1 << (q - 3);
      #pragma unroll
      for (int t = cnt - 1; t >= 0; --t) {
        const float v = sv[t];
        sv[2 * t + 1] = v * sq[q];
        sv[2 * t]     = v * cq[q];
      }
    }
    float* dst = &S[sam * SPAD + oct * 16];
    #pragma unroll
    for (int j4 = 0; j4 < 4; ++j4)
      *(float4*)(dst + j4 * 4) =
          make_float4(sv[4 * j4], sv[4 * j4 + 1], sv[4 * j4 + 2], sv[4 * j4 + 3]);
  }

  const int col = tid & 31;
  const int row = tid >> 5;
  float4 ar[4], ai[4];
  #pragma unroll
  for (int t = 0; t < 4; ++t) {
    ar[t] = make_float4(0.f, 0.f, 0.f, 0.f);
    ai[t] = make_float4(0.f, 0.f, 0.f, 0.f);
  }
  const float* Sb = &S[(row * 4) * SPAD];
  const float4* __restrict__ Ug4 = (const float4*)Up;

  // stage chunk 0 (one float4 per thread = 8 k-values = 2048 floats)
  *(float4*)&Ub[0][tid * 4] = Ug4[tid];
  __syncthreads();

  // ---- phase 2: Y = S * U^T, U double-buffered through LDS ----
  for (int c = 0; c < 16; ++c) {
    float4 pf;
    if (c < 15) pf = Ug4[(c + 1) * 512 + tid];   // prefetch next chunk
    const float4* __restrict__ Uc = (const float4*)Ub[c & 1];
    #pragma unroll
    for (int kl = 0; kl < 2; ++kl) {
      const int k4 = c * 2 + kl;
      float4 su[4];
      #pragma unroll
      for (int t = 0; t < 4; ++t)
        su[t] = *(const float4*)(Sb + t * SPAD + k4 * 4);
      #pragma unroll
      for (int e = 0; e < 4; ++e) {
        const float4 ur = Uc[(kl * 4 + e) * 64 + col];
        const float4 ui = Uc[(kl * 4 + e) * 64 + 32 + col];
        #pragma unroll
        for (int t = 0; t < 4; ++t) {
          const float sx = (&su[t].x)[e];
          FMA4(ar[t], ur, sx);
          FMA4(ai[t], ui, sx);
        }
      }
    }
    if (c < 15) {
      *(float4*)&Ub[(c + 1) & 1][tid * 4] = pf;
      __syncthreads();
    }
  }

  // ---- phase 3: probs, sign-fold to 7 expvals, butterfly over 32 cols ----
  float qa[4][7];
  #pragma unroll
  for (int t = 0; t < 4; ++t) {
    const float p0 = ar[t].x * ar[t].x + ai[t].x * ai[t].x;
    const float p1 = ar[t].y * ar[t].y + ai[t].y * ai[t].y;
    const float p2 = ar[t].z * ar[t].z + ai[t].z * ai[t].z;
    const float p3 = ar[t].w * ar[t].w + ai[t].w * ai[t].w;
    const float ps = p0 + p1 + p2 + p3;
    #pragma unroll
    for (int w = 0; w < 5; ++w)
      qa[t][w] = ((col >> (4 - w)) & 1) ? -ps : ps;
    qa[t][5] = p0 + p1 - p2 - p3;
    qa[t][6] = p0 - p1 + p2 - p3;
  }
  #pragma unroll
  for (int m = 1; m <= 16; m <<= 1) {
    #pragma unroll
    for (int t = 0; t < 4; ++t)
      #pragma unroll
      for (int w = 0; w < 7; ++w)
        qa[t][w] += __shfl_xor(qa[t][w], m);
  }

  // ---- phase 4: MLP; column o (<22) emits logit o for its 4 samples ----
  if (col < 22) {
    #pragma unroll
    for (int t = 0; t < 4; ++t) {
      float h[16];
      #pragma unroll
      for (int k = 0; k < 16; ++k) {
        float acc = b1[k];
        #pragma unroll
        for (int q = 0; q < 7; ++q) acc += W1[k * 7 + q] * qa[t][q];
        h[k] = fmaxf(acc, 0.f);
      }
      float lg = b2[col];
      #pragma unroll
      for (int k = 0; k < 16; ++k) lg += W2[col * 16 + k] * h[k];
      out[(s0 + row * 4 + t) * 22 + col] = lg;
    }
  }
}

extern "C" void kernel_launch(void* const* d_in, const int* in_sizes, int n_in,
                              void* d_out, int out_size, void* d_ws, size_t ws_size,
                              hipStream_t stream) {
  const float* x  = (const float*)d_in[0];
  const float* qw = (const float*)d_in[1];
  const float* W1 = (const float*)d_in[2];
  const float* b1 = (const float*)d_in[3];
  const float* W2 = (const float*)d_in[4];
  const float* b2 = (const float*)d_in[5];
  float* out = (float*)d_out;
  float* Up  = (float*)d_ws;  // 128*256*4 = 128 KiB scratch

  const int B = in_sizes[0] / 7;

  build_unitary_k<<<32, 256, 0, stream>>>(qw, Up);

  const int blocks = (B + MBLK - 1) / MBLK;
  vqc_mlp_k<<<blocks, 512, 0, stream>>>(x, Up, W1, b1, W2, b2, out);
}

// Round 5
// 92.057 us; speedup vs baseline: 3.4976x; 1.1898x over previous
//
#include <hip/hip_runtime.h>
#include <math.h>

#define DIM 128

typedef __attribute__((ext_vector_type(8))) short bf16x8;
typedef __attribute__((ext_vector_type(4))) float f32x4;

// RNE f32 -> bf16 bit helpers (self-contained, exact round-to-nearest-even)
static __device__ __forceinline__ unsigned short f2bf(float v) {
  unsigned u = __float_as_uint(v);
  unsigned r = (u + 0x7FFFu + ((u >> 16) & 1u)) >> 16;
  return (unsigned short)r;
}
static __device__ __forceinline__ float bf2f(unsigned short u) {
  return __uint_as_float(((unsigned)u) << 16);
}

// ---------------- Kernel 1: build U in MFMA B-fragment layout --------------
// One wave per 1 k-column group; lane l holds amplitudes n=l, n+64 (+imag).
// Output: Bhi/Blo bf16 arrays in fragment layout:
//   frag(ct,kt): 64 lanes x 8 bf16; element (lane,e) = Bl[n][k],
//   n = ct*16 + (lane&15), k = kt*32 + (lane>>4)*8 + e,
//   Bl[n][k] = (n<128) ? Re U[n][k] : Im U[n-128][k].
__global__ __launch_bounds__(256) void build_unitary_k(
    const float* __restrict__ qw, unsigned short* __restrict__ Bhi,
    unsigned short* __restrict__ Blo) {
  __shared__ float gm[35][8];  // U00r,U00i,U01r,U01i,U10r,U10i,U11r,U11i
  const int tid = threadIdx.x;

  if (tid < 35) {
    const float phi = qw[tid * 3 + 0];
    const float th  = qw[tid * 3 + 1];
    const float om  = qw[tid * 3 + 2];
    float sh, ch; sincosf(0.5f * th, &sh, &ch);
    const float a = 0.5f * (phi + om);
    const float b = 0.5f * (phi - om);
    float sa, ca; sincosf(a, &sa, &ca);
    float sb, cb; sincosf(b, &sb, &cb);
    gm[tid][0] =  ca * ch;  gm[tid][1] = -sa * ch;   // U00 = e^{-ia} c
    gm[tid][2] = -cb * sh;  gm[tid][3] = -sb * sh;   // U01 = -e^{+ib} s
    gm[tid][4] =  cb * sh;  gm[tid][5] = -sb * sh;   // U10 = e^{-ib} s
    gm[tid][6] =  ca * ch;  gm[tid][7] =  sa * ch;   // U11 = e^{+ia} c
  }
  __syncthreads();

  const int lane = tid & 63;
  const int k    = blockIdx.x * 4 + (tid >> 6);   // basis-state column

  float rl = (k == lane)      ? 1.f : 0.f;
  float rh = (k == lane + 64) ? 1.f : 0.f;
  float il = 0.f, ih = 0.f;

  for (int l = 0; l < 5; ++l) {
    const int r = l % 6 + 1;
    for (int q = 0; q < 7; ++q) {
      const float* g = gm[l * 7 + q];
      const float g0 = g[0], g1 = g[1], g2 = g[2], g3 = g[3];
      const float g4 = g[4], g5 = g[5], g6 = g[6], g7 = g[7];
      if (q == 0) {
        const float nrl = g0 * rl - g1 * il + g2 * rh - g3 * ih;
        const float nil = g0 * il + g1 * rl + g2 * ih + g3 * rh;
        const float nrh = g4 * rl - g5 * il + g6 * rh - g7 * ih;
        const float nih = g4 * il + g5 * rl + g6 * ih + g7 * rh;
        rl = nrl; il = nil; rh = nrh; ih = nih;
      } else {
        const int m = 1 << (6 - q);
        const int bit = (lane & m) ? 1 : 0;
        const float prl = __shfl_xor(rl, m), pil = __shfl_xor(il, m);
        const float prh = __shfl_xor(rh, m), pih = __shfl_xor(ih, m);
        const float udr = bit ? g6 : g0, udi = bit ? g7 : g1;
        const float uor = bit ? g4 : g2, uoi = bit ? g5 : g3;
        const float nrl = udr * rl - udi * il + uor * prl - uoi * pil;
        const float nil = udr * il + udi * rl + uor * pil + uoi * prl;
        const float nrh = udr * rh - udi * ih + uor * prh - uoi * pih;
        const float nih = udr * ih + udi * rh + uor * pih + uoi * prh;
        rl = nrl; il = nil; rh = nrh; ih = nih;
      }
    }
    for (int q = 0; q < 7; ++q) {
      const int tg = (q + r) % 7;
      if (q == 0) {
        const int mt = 1 << (6 - tg);
        const float prh = __shfl_xor(rh, mt), pih = __shfl_xor(ih, mt);
        rh = prh; ih = pih;
      } else if (tg == 0) {
        const int mc = 1 << (6 - q);
        const bool cb = (lane & mc) != 0;
        const float trl = cb ? rh : rl, til = cb ? ih : il;
        const float trh = cb ? rl : rh, tih = cb ? il : ih;
        rl = trl; il = til; rh = trh; ih = tih;
      } else {
        const int mc = 1 << (6 - q), mt = 1 << (6 - tg);
        const bool cb = (lane & mc) != 0;
        const float prl = __shfl_xor(rl, mt), pil = __shfl_xor(il, mt);
        const float prh = __shfl_xor(rh, mt), pih = __shfl_xor(ih, mt);
        rl = cb ? prl : rl; il = cb ? pil : il;
        rh = cb ? prh : rh; ih = cb ? pih : ih;
      }
    }
  }

  const int kt = k >> 5, kl = (k >> 3) & 3, e = k & 7;
  {
    const float vals[4] = {rl, rh, il, ih};
    #pragma unroll
    for (int t = 0; t < 4; ++t) {
      const int n = lane + t * 64;
      const int off = (((n >> 4) * 4 + kt) * 64 + kl * 16 + (n & 15)) * 8 + e;
      const unsigned short h = f2bf(vals[t]);
      Bhi[off] = h;
      Blo[off] = f2bf(vals[t] - bf2f(h));
    }
  }
}

// ---------------- Kernel 2: split-bf16 MFMA GEMM + expvals + MLP ----------
// Block: 512 threads = 8 waves, 32 samples. Wave w: col-tiles {w (Re), w+8 (Im)}
// held in registers; A (S-tile) bf16 hi/lo fragments in LDS.
__global__ __launch_bounds__(512, 4) void vqc_mlp_k(
    const float* __restrict__ x,
    const unsigned short* __restrict__ Bhi, const unsigned short* __restrict__ Blo,
    const float* __restrict__ W1, const float* __restrict__ b1,
    const float* __restrict__ W2, const float* __restrict__ b2,
    float* __restrict__ out) {
  __shared__ unsigned short Ahi[32 * 136];   // 136 = 128 + 8 pad (bank spread)
  __shared__ unsigned short Alo[32 * 136];
  __shared__ float qaP[8 * 32 * 8];          // [wave][sample][wire, pad to 8]
  const int tid  = threadIdx.x;
  const int lane = tid & 63;
  const int w    = tid >> 6;
  const int s0   = blockIdx.x * 32;

  // ---- B fragments -> registers (issue early; L2/L3-hot, coalesced b128) ----
  const bf16x8* __restrict__ Bh8 = (const bf16x8*)Bhi;
  const bf16x8* __restrict__ Bl8 = (const bf16x8*)Blo;
  bf16x8 bh[2][4], bl[2][4];
  #pragma unroll
  for (int t = 0; t < 2; ++t) {
    const int ct = w + t * 8;
    #pragma unroll
    for (int kt = 0; kt < 4; ++kt) {
      bh[t][kt] = Bh8[(ct * 4 + kt) * 64 + lane];
      bl[t][kt] = Bl8[(ct * 4 + kt) * 64 + lane];
    }
  }

  // ---- A tile: product state -> bf16 hi/lo fragments (16 thr/sample) ----
  {
    const int sam = tid >> 4;       // 0..31
    const int ko  = tid & 15;       // k-group: k = ko*8 + e
    const float* xp = x + (s0 + sam) * 7;
    float cq[7], sq[7];
    #pragma unroll
    for (int q = 0; q < 7; ++q) sincosf(0.5f * xp[q], &sq[q], &cq[q]);
    // k bits 6..3 = ko bits 3..0 (wires 0..3); k bits 2..0 = e (wires 4..6)
    float sv[8];
    sv[0] = ((ko & 8) ? sq[0] : cq[0]) * ((ko & 4) ? sq[1] : cq[1]) *
            ((ko & 2) ? sq[2] : cq[2]) * ((ko & 1) ? sq[3] : cq[3]);
    #pragma unroll
    for (int q = 4; q < 7; ++q) {
      const int cnt = 1 << (q - 4);
      #pragma unroll
      for (int t2 = cnt - 1; t2 >= 0; --t2) {
        const float v = sv[t2];
        sv[2 * t2 + 1] = v * sq[q];
        sv[2 * t2]     = v * cq[q];
      }
    }
    bf16x8 h8, l8;
    #pragma unroll
    for (int e = 0; e < 8; ++e) {
      const unsigned short h = f2bf(sv[e]);
      h8[e] = (short)h;
      l8[e] = (short)f2bf(sv[e] - bf2f(h));
    }
    *(bf16x8*)&Ahi[sam * 136 + ko * 8] = h8;
    *(bf16x8*)&Alo[sam * 136 + ko * 8] = l8;
  }
  __syncthreads();

  // ---- main loop: 3-term split-bf16 MFMA, K=128 in 4 steps of 32 ----
  f32x4 acc00 = {0.f, 0.f, 0.f, 0.f};  // sample-tile 0, Re
  f32x4 acc01 = {0.f, 0.f, 0.f, 0.f};  // sample-tile 0, Im
  f32x4 acc10 = {0.f, 0.f, 0.f, 0.f};  // sample-tile 1, Re
  f32x4 acc11 = {0.f, 0.f, 0.f, 0.f};  // sample-tile 1, Im
  const int r0 = (lane & 15) * 136;
  const int r1 = (16 + (lane & 15)) * 136;
  const int kloff = (lane >> 4) * 8;
  #pragma unroll
  for (int kt = 0; kt < 4; ++kt) {
    const int ko2 = kt * 32 + kloff;
    const bf16x8 ah0 = *(const bf16x8*)&Ahi[r0 + ko2];
    const bf16x8 al0 = *(const bf16x8*)&Alo[r0 + ko2];
    const bf16x8 ah1 = *(const bf16x8*)&Ahi[r1 + ko2];
    const bf16x8 al1 = *(const bf16x8*)&Alo[r1 + ko2];
    acc00 = __builtin_amdgcn_mfma_f32_16x16x32_bf16(ah0, bh[0][kt], acc00, 0, 0, 0);
    acc01 = __builtin_amdgcn_mfma_f32_16x16x32_bf16(ah0, bh[1][kt], acc01, 0, 0, 0);
    acc10 = __builtin_amdgcn_mfma_f32_16x16x32_bf16(ah1, bh[0][kt], acc10, 0, 0, 0);
    acc11 = __builtin_amdgcn_mfma_f32_16x16x32_bf16(ah1, bh[1][kt], acc11, 0, 0, 0);
    acc00 = __builtin_amdgcn_mfma_f32_16x16x32_bf16(ah0, bl[0][kt], acc00, 0, 0, 0);
    acc01 = __builtin_amdgcn_mfma_f32_16x16x32_bf16(ah0, bl[1][kt], acc01, 0, 0, 0);
    acc10 = __builtin_amdgcn_mfma_f32_16x16x32_bf16(ah1, bl[0][kt], acc10, 0, 0, 0);
    acc11 = __builtin_amdgcn_mfma_f32_16x16x32_bf16(ah1, bl[1][kt], acc11, 0, 0, 0);
    acc00 = __builtin_amdgcn_mfma_f32_16x16x32_bf16(al0, bh[0][kt], acc00, 0, 0, 0);
    acc01 = __builtin_amdgcn_mfma_f32_16x16x32_bf16(al0, bh[1][kt], acc01, 0, 0, 0);
    acc10 = __builtin_amdgcn_mfma_f32_16x16x32_bf16(al1, bh[0][kt], acc10, 0, 0, 0);
    acc11 = __builtin_amdgcn_mfma_f32_16x16x32_bf16(al1, bh[1][kt], acc11, 0, 0, 0);
  }

  // ---- epilogue: p = yr^2 + yi^2; signed-WHT butterfly over lane bits ----
  // col n = 16*w + c, c = lane&15. Wire signs: wire0<-bit6=(w>>2), wire1<-bit5,
  // wire2<-bit4 (wave-uniform); wires 3..6 <- bits 3..0 of c (butterfly).
  const int c  = lane & 15;
  const int lg = lane >> 4;
  float u[2][4][5];   // [sample-tile][reg r][0=plain, 1..4 = wire3..6 diffs]
  #pragma unroll
  for (int st = 0; st < 2; ++st) {
    const f32x4 yr = (st == 0) ? acc00 : acc10;
    const f32x4 yi = (st == 0) ? acc01 : acc11;
    #pragma unroll
    for (int r = 0; r < 4; ++r) {
      const float p = yr[r] * yr[r] + yi[r] * yi[r];
      #pragma unroll
      for (int a = 0; a < 5; ++a) u[st][r][a] = p;
    }
  }
  #pragma unroll
  for (int stg = 0; stg < 4; ++stg) {
    const int m = 8 >> stg;     // masks 8,4,2,1 <-> wires 3,4,5,6
    const int di = stg + 1;
    #pragma unroll
    for (int st = 0; st < 2; ++st)
      #pragma unroll
      for (int r = 0; r < 4; ++r)
        #pragma unroll
        for (int a = 0; a < 5; ++a) {
          const float xv = __shfl_xor(u[st][r][a], m);
          if (a == di) u[st][r][a] = (c & m) ? (xv - u[st][r][a]) : (u[st][r][a] - xv);
          else         u[st][r][a] += xv;
        }
  }
  const int sg0 = (w >> 2) & 1, sg1 = (w >> 1) & 1, sg2 = w & 1;
  if (c < 7) {
    #pragma unroll
    for (int st = 0; st < 2; ++st)
      #pragma unroll
      for (int r = 0; r < 4; ++r) {
        const float u0 = u[st][r][0];
        float v;
        if (c == 0)      v = sg0 ? -u0 : u0;
        else if (c == 1) v = sg1 ? -u0 : u0;
        else if (c == 2) v = sg2 ? -u0 : u0;
        else if (c == 3) v = u[st][r][1];
        else if (c == 4) v = u[st][r][2];
        else if (c == 5) v = u[st][r][3];
        else             v = u[st][r][4];
        qaP[w * 256 + (st * 16 + lg * 4 + r) * 8 + c] = v;
      }
  }
  __syncthreads();

  // ---- MLP: thread (s, oo) computes logits oo and oo+11 for sample s ----
  if (tid < 352) {
    const int s  = tid / 11;
    const int oo = tid - s * 11;
    float qv[7];
    #pragma unroll
    for (int q = 0; q < 7; ++q) {
      float a2 = 0.f;
      #pragma unroll
      for (int wv = 0; wv < 8; ++wv) a2 += qaP[wv * 256 + s * 8 + q];
      qv[q] = a2;
    }
    float h[16];
    #pragma unroll
    for (int k = 0; k < 16; ++k) {
      float a2 = b1[k];
      #pragma unroll
      for (int q = 0; q < 7; ++q) a2 += W1[k * 7 + q] * qv[q];
      h[k] = fmaxf(a2, 0.f);
    }
    #pragma unroll
    for (int oi = 0; oi < 2; ++oi) {
      const int o = oo + oi * 11;
      float lg2 = b2[o];
      #pragma unroll
      for (int k = 0; k < 16; ++k) lg2 += W2[o * 16 + k] * h[k];
      out[(s0 + s) * 22 + o] = lg2;
    }
  }
}

extern "C" void kernel_launch(void* const* d_in, const int* in_sizes, int n_in,
                              void* d_out, int out_size, void* d_ws, size_t ws_size,
                              hipStream_t stream) {
  const float* x  = (const float*)d_in[0];
  const float* qw = (const float*)d_in[1];
  const float* W1 = (const float*)d_in[2];
  const float* b1 = (const float*)d_in[3];
  const float* W2 = (const float*)d_in[4];
  const float* b2 = (const float*)d_in[5];
  float* out = (float*)d_out;
  unsigned short* Bhi = (unsigned short*)d_ws;            // 64 KiB
  unsigned short* Blo = Bhi + 128 * 256;                  // 64 KiB

  const int B = in_sizes[0] / 7;

  build_unitary_k<<<32, 256, 0, stream>>>(qw, Bhi, Blo);

  vqc_mlp_k<<<B / 32, 512, 0, stream>>>(x, Bhi, Blo, W1, b1, W2, b2, out);
}

// Round 9
// 82.373 us; speedup vs baseline: 3.9088x; 1.1176x over previous
//
#include <hip/hip_runtime.h>
#include <math.h>

#define DIM 128

typedef __attribute__((ext_vector_type(8))) short bf16x8;
typedef __attribute__((ext_vector_type(4))) float f32x4;

// RNE f32 -> bf16 bit helpers
static __device__ __forceinline__ unsigned short f2bf(float v) {
  unsigned u = __float_as_uint(v);
  unsigned r = (u + 0x7FFFu + ((u >> 16) & 1u)) >> 16;
  return (unsigned short)r;
}
static __device__ __forceinline__ float bf2f(unsigned short u) {
  return __uint_as_float(((unsigned)u) << 16);
}

// ---------------- Kernel 1: build U in MFMA fragment layout ----------------
// frag(ct,kt): elem (lane,e) = Bl[n][k], n = ct*16+(lane&15),
// k = kt*32+(lane>>4)*8+e, Bl[n][k] = (n<128)? Re U[n][k] : Im U[n-128][k].
__global__ __launch_bounds__(256) void build_unitary_k(
    const float* __restrict__ qw, unsigned short* __restrict__ Bhi,
    unsigned short* __restrict__ Blo) {
  __shared__ float gm[35][8];
  const int tid = threadIdx.x;

  if (tid < 35) {
    const float phi = qw[tid * 3 + 0];
    const float th  = qw[tid * 3 + 1];
    const float om  = qw[tid * 3 + 2];
    float sh, ch; sincosf(0.5f * th, &sh, &ch);
    const float a = 0.5f * (phi + om);
    const float b = 0.5f * (phi - om);
    float sa, ca; sincosf(a, &sa, &ca);
    float sb, cb; sincosf(b, &sb, &cb);
    gm[tid][0] =  ca * ch;  gm[tid][1] = -sa * ch;
    gm[tid][2] = -cb * sh;  gm[tid][3] = -sb * sh;
    gm[tid][4] =  cb * sh;  gm[tid][5] = -sb * sh;
    gm[tid][6] =  ca * ch;  gm[tid][7] =  sa * ch;
  }
  __syncthreads();

  const int lane = tid & 63;
  const int k    = blockIdx.x * 4 + (tid >> 6);

  float rl = (k == lane)      ? 1.f : 0.f;
  float rh = (k == lane + 64) ? 1.f : 0.f;
  float il = 0.f, ih = 0.f;

  for (int l = 0; l < 5; ++l) {
    const int r = l % 6 + 1;
    for (int q = 0; q < 7; ++q) {
      const float* g = gm[l * 7 + q];
      const float g0 = g[0], g1 = g[1], g2 = g[2], g3 = g[3];
      const float g4 = g[4], g5 = g[5], g6 = g[6], g7 = g[7];
      if (q == 0) {
        const float nrl = g0 * rl - g1 * il + g2 * rh - g3 * ih;
        const float nil = g0 * il + g1 * rl + g2 * ih + g3 * rh;
        const float nrh = g4 * rl - g5 * il + g6 * rh - g7 * ih;
        const float nih = g4 * il + g5 * rl + g6 * ih + g7 * rh;
        rl = nrl; il = nil; rh = nrh; ih = nih;
      } else {
        const int m = 1 << (6 - q);
        const int bit = (lane & m) ? 1 : 0;
        const float prl = __shfl_xor(rl, m), pil = __shfl_xor(il, m);
        const float prh = __shfl_xor(rh, m), pih = __shfl_xor(ih, m);
        const float udr = bit ? g6 : g0, udi = bit ? g7 : g1;
        const float uor = bit ? g4 : g2, uoi = bit ? g5 : g3;
        const float nrl = udr * rl - udi * il + uor * prl - uoi * pil;
        const float nil = udr * il + udi * rl + uor * pil + uoi * prl;
        const float nrh = udr * rh - udi * ih + uor * prh - uoi * pih;
        const float nih = udr * ih + udi * rh + uor * pih + uoi * prh;
        rl = nrl; il = nil; rh = nrh; ih = nih;
      }
    }
    for (int q = 0; q < 7; ++q) {
      const int tg = (q + r) % 7;
      if (q == 0) {
        const int mt = 1 << (6 - tg);
        const float prh = __shfl_xor(rh, mt), pih = __shfl_xor(ih, mt);
        rh = prh; ih = pih;
      } else if (tg == 0) {
        const int mc = 1 << (6 - q);
        const bool cb = (lane & mc) != 0;
        const float trl = cb ? rh : rl, til = cb ? ih : il;
        const float trh = cb ? rl : rh, tih = cb ? il : ih;
        rl = trl; il = til; rh = trh; ih = tih;
      } else {
        const int mc = 1 << (6 - q), mt = 1 << (6 - tg);
        const bool cb = (lane & mc) != 0;
        const float prl = __shfl_xor(rl, mt), pil = __shfl_xor(il, mt);
        const float prh = __shfl_xor(rh, mt), pih = __shfl_xor(ih, mt);
        rl = cb ? prl : rl; il = cb ? pil : il;
        rh = cb ? prh : rh; ih = cb ? pih : ih;
      }
    }
  }

  const int kt = k >> 5, kl = (k >> 3) & 3, e = k & 7;
  {
    const float vals[4] = {rl, rh, il, ih};
    #pragma unroll
    for (int t = 0; t < 4; ++t) {
      const int n = lane + t * 64;
      const int off = (((n >> 4) * 4 + kt) * 64 + kl * 16 + (n & 15)) * 8 + e;
      const unsigned short h = f2bf(vals[t]);
      Bhi[off] = h;
      Blo[off] = f2bf(vals[t] - bf2f(h));
    }
  }
}

// ---------------- Kernel 2: swapped-operand MFMA GEMM + cheap epilogue ----
// Block: 512 thr = 8 waves, 32 samples. Wave w: A = U row-tiles {w (Re), w+8 (Im)}
// in registers; B = S-frags in LDS. D layout: col (lane&15) = sample,
// row ((lane>>4)*4+r) = u-sub-index -> wires 5,6 reduce IN-LANE.
__global__ __launch_bounds__(512, 4) void vqc_mlp_k(
    const float* __restrict__ x,
    const unsigned short* __restrict__ Bhi, const unsigned short* __restrict__ Blo,
    const float* __restrict__ W1, const float* __restrict__ b1,
    const float* __restrict__ W2, const float* __restrict__ b2,
    float* __restrict__ out) {
  __shared__ float smem[4608];
  unsigned short* Ahi = (unsigned short*)smem;            // ushorts [0, 4352)  = floats [0, 2176)
  unsigned short* Alo = (unsigned short*)(smem + 2176);   // ushorts [4352, 8704) = floats [2176, 4352)
  float* qaP = smem;                                      // alias (post-MFMA): [8][32][9] = 2304 floats
  float* QA  = smem + 2304;                               // [32][8] = 256 floats

  const int tid  = threadIdx.x;
  const int lane = tid & 63;
  const int w    = tid >> 6;
  const int s0   = blockIdx.x * 32;

  // ---- U fragments -> registers (L2-hot, coalesced b128) ----
  const bf16x8* __restrict__ Bh8 = (const bf16x8*)Bhi;
  const bf16x8* __restrict__ Bl8 = (const bf16x8*)Blo;
  bf16x8 bh[2][4], bl[2][4];
  #pragma unroll
  for (int t = 0; t < 2; ++t) {
    const int ct = w + t * 8;
    #pragma unroll
    for (int kt = 0; kt < 4; ++kt) {
      bh[t][kt] = Bh8[(ct * 4 + kt) * 64 + lane];
      bl[t][kt] = Bl8[(ct * 4 + kt) * 64 + lane];
    }
  }

  // ---- S tile: product state -> bf16 hi/lo fragments (16 thr/sample) ----
  {
    const int sam = tid >> 4;       // 0..31
    const int ko  = tid & 15;       // k = ko*8 + e
    const float* xp = x + (s0 + sam) * 7;
    float cq[7], sq[7];
    #pragma unroll
    for (int q = 0; q < 7; ++q) __sincosf(0.5f * xp[q], &sq[q], &cq[q]);
    float sv[8];
    sv[0] = ((ko & 8) ? sq[0] : cq[0]) * ((ko & 4) ? sq[1] : cq[1]) *
            ((ko & 2) ? sq[2] : cq[2]) * ((ko & 1) ? sq[3] : cq[3]);
    #pragma unroll
    for (int q = 4; q < 7; ++q) {
      const int cnt = 1 << (q - 4);
      #pragma unroll
      for (int t2 = cnt - 1; t2 >= 0; --t2) {
        const float v = sv[t2];
        sv[2 * t2 + 1] = v * sq[q];
        sv[2 * t2]     = v * cq[q];
      }
    }
    bf16x8 h8, l8;
    #pragma unroll
    for (int e = 0; e < 8; ++e) {
      const unsigned short h = f2bf(sv[e]);
      h8[e] = (short)h;
      l8[e] = (short)f2bf(sv[e] - bf2f(h));
    }
    *(bf16x8*)&Ahi[sam * 136 + ko * 8] = h8;
    *(bf16x8*)&Alo[sam * 136 + ko * 8] = l8;
  }
  __syncthreads();

  // ---- main loop: D[u-idx][sample]; 3-term split-bf16, K=128 ----
  f32x4 acc00 = {0.f, 0.f, 0.f, 0.f};  // Re, samples 0-15
  f32x4 acc01 = {0.f, 0.f, 0.f, 0.f};  // Im, samples 0-15
  f32x4 acc10 = {0.f, 0.f, 0.f, 0.f};  // Re, samples 16-31
  f32x4 acc11 = {0.f, 0.f, 0.f, 0.f};  // Im, samples 16-31
  const int r0 = (lane & 15) * 136;
  const int r1 = (16 + (lane & 15)) * 136;
  const int kloff = (lane >> 4) * 8;
  #pragma unroll
  for (int kt = 0; kt < 4; ++kt) {
    const int ko2 = kt * 32 + kloff;
    const bf16x8 ah0 = *(const bf16x8*)&Ahi[r0 + ko2];
    const bf16x8 al0 = *(const bf16x8*)&Alo[r0 + ko2];
    const bf16x8 ah1 = *(const bf16x8*)&Ahi[r1 + ko2];
    const bf16x8 al1 = *(const bf16x8*)&Alo[r1 + ko2];
    acc00 = __builtin_amdgcn_mfma_f32_16x16x32_bf16(bh[0][kt], ah0, acc00, 0, 0, 0);
    acc01 = __builtin_amdgcn_mfma_f32_16x16x32_bf16(bh[1][kt], ah0, acc01, 0, 0, 0);
    acc10 = __builtin_amdgcn_mfma_f32_16x16x32_bf16(bh[0][kt], ah1, acc10, 0, 0, 0);
    acc11 = __builtin_amdgcn_mfma_f32_16x16x32_bf16(bh[1][kt], ah1, acc11, 0, 0, 0);
    acc00 = __builtin_amdgcn_mfma_f32_16x16x32_bf16(bl[0][kt], ah0, acc00, 0, 0, 0);
    acc01 = __builtin_amdgcn_mfma_f32_16x16x32_bf16(bl[1][kt], ah0, acc01, 0, 0, 0);
    acc10 = __builtin_amdgcn_mfma_f32_16x16x32_bf16(bl[0][kt], ah1, acc10, 0, 0, 0);
    acc11 = __builtin_amdgcn_mfma_f32_16x16x32_bf16(bl[1][kt], ah1, acc11, 0, 0, 0);
    acc00 = __builtin_amdgcn_mfma_f32_16x16x32_bf16(bh[0][kt], al0, acc00, 0, 0, 0);
    acc01 = __builtin_amdgcn_mfma_f32_16x16x32_bf16(bh[1][kt], al0, acc01, 0, 0, 0);
    acc10 = __builtin_amdgcn_mfma_f32_16x16x32_bf16(bh[0][kt], al1, acc10, 0, 0, 0);
    acc11 = __builtin_amdgcn_mfma_f32_16x16x32_bf16(bh[1][kt], al1, acc11, 0, 0, 0);
  }

  // ---- epilogue: i = w*16 + (lane>>4)*4 + r. wires 5,6 <- r bits (in-lane);
  // wires 3,4 <- lane bits 5,4 (2 shfl stages); wires 0-2 <- w bits (signs) ----
  const int sg0 = (w >> 2) & 1, sg1 = (w >> 1) & 1, sg2 = w & 1;
  float qv7[2][7];
  #pragma unroll
  for (int st = 0; st < 2; ++st) {
    const f32x4 yr = (st == 0) ? acc00 : acc10;
    const f32x4 yi = (st == 0) ? acc01 : acc11;
    const float p0 = yr[0] * yr[0] + yi[0] * yi[0];
    const float p1 = yr[1] * yr[1] + yi[1] * yi[1];
    const float p2 = yr[2] * yr[2] + yi[2] * yi[2];
    const float p3 = yr[3] * yr[3] + yi[3] * yi[3];
    const float t  = p0 + p1 + p2 + p3;
    const float d5 = p0 + p1 - p2 - p3;   // wire5 <- i bit1 (reg bit1)
    const float d6 = p0 - p1 + p2 - p3;   // wire6 <- i bit0 (reg bit0)
    const float t16 = __shfl_xor(t, 16);
    const float a   = t + t16;
    const float b4  = (lane & 16) ? (t16 - t) : (t - t16);   // wire4 <- i bit2
    const float a32 = __shfl_xor(a, 32);
    const float T   = a + a32;
    const float D3  = (lane & 32) ? (a32 - a) : (a - a32);   // wire3 <- i bit3
    const float D4  = b4 + __shfl_xor(b4, 32);
    const float d5a = d5 + __shfl_xor(d5, 16);
    const float D5  = d5a + __shfl_xor(d5a, 32);
    const float d6a = d6 + __shfl_xor(d6, 16);
    const float D6  = d6a + __shfl_xor(d6a, 32);
    qv7[st][0] = sg0 ? -T : T;
    qv7[st][1] = sg1 ? -T : T;
    qv7[st][2] = sg2 ? -T : T;
    qv7[st][3] = D3; qv7[st][4] = D4; qv7[st][5] = D5; qv7[st][6] = D6;
  }
  __syncthreads();   // A-frag reads done everywhere; safe to alias qaP

  if (lane < 16) {
    #pragma unroll
    for (int st = 0; st < 2; ++st) {
      const int base = w * 288 + (st * 16 + lane) * 9;
      #pragma unroll
      for (int q = 0; q < 7; ++q) qaP[base + q] = qv7[st][q];
    }
  }
  __syncthreads();

  // ---- reduce over waves: thread (q = tid>>5, s = tid&31), q < 7 ----
  if (tid < 224) {
    const int q = tid >> 5, s = tid & 31;
    float acc = 0.f;
    #pragma unroll
    for (int wv = 0; wv < 8; ++wv) acc += qaP[wv * 288 + s * 9 + q];
    QA[s * 8 + q] = acc;
  }
  __syncthreads();

  // ---- MLP: thread (s, oo) computes logits oo and oo+11 for sample s ----
  if (tid < 352) {
    const int s  = tid / 11;
    const int oo = tid - s * 11;
    float qv[7];
    #pragma unroll
    for (int q = 0; q < 7; ++q) qv[q] = QA[s * 8 + q];
    float h[16];
    #pragma unroll
    for (int k = 0; k < 16; ++k) {
      float a2 = b1[k];
      #pragma unroll
      for (int q = 0; q < 7; ++q) a2 += W1[k * 7 + q] * qv[q];
      h[k] = fmaxf(a2, 0.f);
    }
    #pragma unroll
    for (int oi = 0; oi < 2; ++oi) {
      const int o = oo + oi * 11;
      float lg2 = b2[o];
      #pragma unroll
      for (int k = 0; k < 16; ++k) lg2 += W2[o * 16 + k] * h[k];
      out[(s0 + s) * 22 + o] = lg2;
    }
  }
}

extern "C" void kernel_launch(void* const* d_in, const int* in_sizes, int n_in,
                              void* d_out, int out_size, void* d_ws, size_t ws_size,
                              hipStream_t stream) {
  const float* x  = (const float*)d_in[0];
  const float* qw = (const float*)d_in[1];
  const float* W1 = (const float*)d_in[2];
  const float* b1 = (const float*)d_in[3];
  const float* W2 = (const float*)d_in[4];
  const float* b2 = (const float*)d_in[5];
  float* out = (float*)d_out;
  unsigned short* Bhi = (unsigned short*)d_ws;            // 64 KiB
  unsigned short* Blo = Bhi + 128 * 256;                  // 64 KiB

  const int B = in_sizes[0] / 7;

  build_unitary_k<<<32, 256, 0, stream>>>(qw, Bhi, Blo);

  vqc_mlp_k<<<B / 32, 512, 0, stream>>>(x, Bhi, Blo, W1, b1, W2, b2, out);
}

// Round 11
// 80.741 us; speedup vs baseline: 3.9878x; 1.0202x over previous
//
#include <hip/hip_runtime.h>
#include <math.h>

#define DIM 128

typedef __attribute__((ext_vector_type(8))) short bf16x8;
typedef __attribute__((ext_vector_type(4))) float f32x4;

// RNE f32 -> bf16 bit helpers
static __device__ __forceinline__ unsigned short f2bf(float v) {
  unsigned u = __float_as_uint(v);
  unsigned r = (u + 0x7FFFu + ((u >> 16) & 1u)) >> 16;
  return (unsigned short)r;
}
static __device__ __forceinline__ float bf2f(unsigned short u) {
  return __uint_as_float(((unsigned)u) << 16);
}

// ---------------- Kernel 1: build U in MFMA fragment layout ----------------
// frag(ct,kt): elem (lane,e) = Bl[n][k], n = ct*16+(lane&15),
// k = kt*32+(lane>>4)*8+e, Bl[n][k] = (n<128)? Re U[n][k] : Im U[n-128][k].
__global__ __launch_bounds__(256) void build_unitary_k(
    const float* __restrict__ qw, unsigned short* __restrict__ Bhi,
    unsigned short* __restrict__ Blo) {
  __shared__ float gm[35][8];
  const int tid = threadIdx.x;

  if (tid < 35) {
    const float phi = qw[tid * 3 + 0];
    const float th  = qw[tid * 3 + 1];
    const float om  = qw[tid * 3 + 2];
    float sh, ch; sincosf(0.5f * th, &sh, &ch);
    const float a = 0.5f * (phi + om);
    const float b = 0.5f * (phi - om);
    float sa, ca; sincosf(a, &sa, &ca);
    float sb, cb; sincosf(b, &sb, &cb);
    gm[tid][0] =  ca * ch;  gm[tid][1] = -sa * ch;
    gm[tid][2] = -cb * sh;  gm[tid][3] = -sb * sh;
    gm[tid][4] =  cb * sh;  gm[tid][5] = -sb * sh;
    gm[tid][6] =  ca * ch;  gm[tid][7] =  sa * ch;
  }
  __syncthreads();

  const int lane = tid & 63;
  const int k    = blockIdx.x * 4 + (tid >> 6);

  float rl = (k == lane)      ? 1.f : 0.f;
  float rh = (k == lane + 64) ? 1.f : 0.f;
  float il = 0.f, ih = 0.f;

  for (int l = 0; l < 5; ++l) {
    const int r = l % 6 + 1;
    for (int q = 0; q < 7; ++q) {
      const float* g = gm[l * 7 + q];
      const float g0 = g[0], g1 = g[1], g2 = g[2], g3 = g[3];
      const float g4 = g[4], g5 = g[5], g6 = g[6], g7 = g[7];
      if (q == 0) {
        const float nrl = g0 * rl - g1 * il + g2 * rh - g3 * ih;
        const float nil = g0 * il + g1 * rl + g2 * ih + g3 * rh;
        const float nrh = g4 * rl - g5 * il + g6 * rh - g7 * ih;
        const float nih = g4 * il + g5 * rl + g6 * ih + g7 * rh;
        rl = nrl; il = nil; rh = nrh; ih = nih;
      } else {
        const int m = 1 << (6 - q);
        const int bit = (lane & m) ? 1 : 0;
        const float prl = __shfl_xor(rl, m), pil = __shfl_xor(il, m);
        const float prh = __shfl_xor(rh, m), pih = __shfl_xor(ih, m);
        const float udr = bit ? g6 : g0, udi = bit ? g7 : g1;
        const float uor = bit ? g4 : g2, uoi = bit ? g5 : g3;
        const float nrl = udr * rl - udi * il + uor * prl - uoi * pil;
        const float nil = udr * il + udi * rl + uor * pil + uoi * prl;
        const float nrh = udr * rh - udi * ih + uor * prh - uoi * pih;
        const float nih = udr * ih + udi * rh + uor * pih + uoi * prh;
        rl = nrl; il = nil; rh = nrh; ih = nih;
      }
    }
    for (int q = 0; q < 7; ++q) {
      const int tg = (q + r) % 7;
      if (q == 0) {
        const int mt = 1 << (6 - tg);
        const float prh = __shfl_xor(rh, mt), pih = __shfl_xor(ih, mt);
        rh = prh; ih = pih;
      } else if (tg == 0) {
        const int mc = 1 << (6 - q);
        const bool cb = (lane & mc) != 0;
        const float trl = cb ? rh : rl, til = cb ? ih : il;
        const float trh = cb ? rl : rh, tih = cb ? il : ih;
        rl = trl; il = til; rh = trh; ih = tih;
      } else {
        const int mc = 1 << (6 - q), mt = 1 << (6 - tg);
        const bool cb = (lane & mc) != 0;
        const float prl = __shfl_xor(rl, mt), pil = __shfl_xor(il, mt);
        const float prh = __shfl_xor(rh, mt), pih = __shfl_xor(ih, mt);
        rl = cb ? prl : rl; il = cb ? pil : il;
        rh = cb ? prh : rh; ih = cb ? pih : ih;
      }
    }
  }

  const int kt = k >> 5, kl = (k >> 3) & 3, e = k & 7;
  {
    const float vals[4] = {rl, rh, il, ih};
    #pragma unroll
    for (int t = 0; t < 4; ++t) {
      const int n = lane + t * 64;
      const int off = (((n >> 4) * 4 + kt) * 64 + kl * 16 + (n & 15)) * 8 + e;
      const unsigned short h = f2bf(vals[t]);
      Bhi[off] = h;
      Blo[off] = f2bf(vals[t] - bf2f(h));
    }
  }
}

// ---------------- Kernel 2: swapped-operand MFMA GEMM + cheap epilogue ----
// Block: 512 thr = 8 waves, 32 samples. Wave w: A = U row-tiles {w (Re), w+8 (Im)},
// loaded per-kt in a rotated prefetch pipeline (8 frags / 32 VGPR in flight);
// B = S-frags in LDS. D: col (lane&15) = sample, row = u-sub-index.
// NOTE: consecutive kt fragments are 64 bf16x8 elements apart (stride 64).
__global__ __launch_bounds__(512, 4) void vqc_mlp_k(
    const float* __restrict__ x,
    const unsigned short* __restrict__ Bhi, const unsigned short* __restrict__ Blo,
    const float* __restrict__ W1, const float* __restrict__ b1,
    const float* __restrict__ W2, const float* __restrict__ b2,
    float* __restrict__ out) {
  __shared__ float smem[4608];
  unsigned short* Ahi = (unsigned short*)smem;            // ushorts [0, 4352)
  unsigned short* Alo = (unsigned short*)(smem + 2176);   // ushorts [4352, 8704)
  float* qaP = smem;                                      // alias (post-MFMA): [8][32][9]
  float* QA  = smem + 2304;                               // [32][8]

  const int tid  = threadIdx.x;
  const int lane = tid & 63;
  const int w    = tid >> 6;
  const int s0   = blockIdx.x * 32;

  const bf16x8* __restrict__ Bh8 = (const bf16x8*)Bhi;
  const bf16x8* __restrict__ Bl8 = (const bf16x8*)Blo;
  const int boff0 = (w * 4) * 64 + lane;          // ct0 = w      (Re rows)
  const int boff1 = ((w + 8) * 4) * 64 + lane;    // ct1 = w + 8  (Im rows)

  // issue kt=0 loads now; latency hides under the S-build VALU phase
  bf16x8 bh0 = Bh8[boff0],      bh1 = Bh8[boff1];
  bf16x8 bl0 = Bl8[boff0],      bl1 = Bl8[boff1];

  // ---- S tile: product state -> bf16 hi/lo fragments (16 thr/sample) ----
  {
    const int sam = tid >> 4;       // 0..31
    const int ko  = tid & 15;       // k = ko*8 + e
    const float* xp = x + (s0 + sam) * 7;
    float cq[7], sq[7];
    #pragma unroll
    for (int q = 0; q < 7; ++q) __sincosf(0.5f * xp[q], &sq[q], &cq[q]);
    float sv[8];
    sv[0] = ((ko & 8) ? sq[0] : cq[0]) * ((ko & 4) ? sq[1] : cq[1]) *
            ((ko & 2) ? sq[2] : cq[2]) * ((ko & 1) ? sq[3] : cq[3]);
    #pragma unroll
    for (int q = 4; q < 7; ++q) {
      const int cnt = 1 << (q - 4);
      #pragma unroll
      for (int t2 = cnt - 1; t2 >= 0; --t2) {
        const float v = sv[t2];
        sv[2 * t2 + 1] = v * sq[q];
        sv[2 * t2]     = v * cq[q];
      }
    }
    bf16x8 h8, l8;
    #pragma unroll
    for (int e = 0; e < 8; ++e) {
      const unsigned short h = f2bf(sv[e]);
      h8[e] = (short)h;
      l8[e] = (short)f2bf(sv[e] - bf2f(h));
    }
    *(bf16x8*)&Ahi[sam * 136 + ko * 8] = h8;
    *(bf16x8*)&Alo[sam * 136 + ko * 8] = l8;
  }
  __syncthreads();

  // ---- main loop: D[u-idx][sample]; 3-term split-bf16, K=128; rotated
  // per-kt B prefetch keeps only 8 fragments (32 VGPR) in flight ----
  f32x4 acc00 = {0.f, 0.f, 0.f, 0.f};  // Re, samples 0-15
  f32x4 acc01 = {0.f, 0.f, 0.f, 0.f};  // Im, samples 0-15
  f32x4 acc10 = {0.f, 0.f, 0.f, 0.f};  // Re, samples 16-31
  f32x4 acc11 = {0.f, 0.f, 0.f, 0.f};  // Im, samples 16-31
  const int r0 = (lane & 15) * 136;
  const int r1 = (16 + (lane & 15)) * 136;
  const int kloff = (lane >> 4) * 8;
  #pragma unroll
  for (int kt = 0; kt < 4; ++kt) {
    bf16x8 nh0, nh1, nl0, nl1;
    if (kt < 3) {                       // prefetch kt+1 during kt's MFMAs
      const int d = (kt + 1) * 64;      // kt fragments are 64 bf16x8 apart
      nh0 = Bh8[boff0 + d];
      nh1 = Bh8[boff1 + d];
      nl0 = Bl8[boff0 + d];
      nl1 = Bl8[boff1 + d];
    }
    const int ko2 = kt * 32 + kloff;
    const bf16x8 ah0 = *(const bf16x8*)&Ahi[r0 + ko2];
    const bf16x8 al0 = *(const bf16x8*)&Alo[r0 + ko2];
    const bf16x8 ah1 = *(const bf16x8*)&Ahi[r1 + ko2];
    const bf16x8 al1 = *(const bf16x8*)&Alo[r1 + ko2];
    acc00 = __builtin_amdgcn_mfma_f32_16x16x32_bf16(bh0, ah0, acc00, 0, 0, 0);
    acc01 = __builtin_amdgcn_mfma_f32_16x16x32_bf16(bh1, ah0, acc01, 0, 0, 0);
    acc10 = __builtin_amdgcn_mfma_f32_16x16x32_bf16(bh0, ah1, acc10, 0, 0, 0);
    acc11 = __builtin_amdgcn_mfma_f32_16x16x32_bf16(bh1, ah1, acc11, 0, 0, 0);
    acc00 = __builtin_amdgcn_mfma_f32_16x16x32_bf16(bl0, ah0, acc00, 0, 0, 0);
    acc01 = __builtin_amdgcn_mfma_f32_16x16x32_bf16(bl1, ah0, acc01, 0, 0, 0);
    acc10 = __builtin_amdgcn_mfma_f32_16x16x32_bf16(bl0, ah1, acc10, 0, 0, 0);
    acc11 = __builtin_amdgcn_mfma_f32_16x16x32_bf16(bl1, ah1, acc11, 0, 0, 0);
    acc00 = __builtin_amdgcn_mfma_f32_16x16x32_bf16(bh0, al0, acc00, 0, 0, 0);
    acc01 = __builtin_amdgcn_mfma_f32_16x16x32_bf16(bh1, al0, acc01, 0, 0, 0);
    acc10 = __builtin_amdgcn_mfma_f32_16x16x32_bf16(bh0, al1, acc10, 0, 0, 0);
    acc11 = __builtin_amdgcn_mfma_f32_16x16x32_bf16(bh1, al1, acc11, 0, 0, 0);
    if (kt < 3) { bh0 = nh0; bh1 = nh1; bl0 = nl0; bl1 = nl1; }
  }

  // ---- epilogue: i = w*16 + (lane>>4)*4 + r. wires 5,6 <- r bits (in-lane);
  // wires 3,4 <- lane bits 5,4 (2 shfl stages); wires 0-2 <- w bits (signs) ----
  const int sg0 = (w >> 2) & 1, sg1 = (w >> 1) & 1, sg2 = w & 1;
  float qv7[2][7];
  #pragma unroll
  for (int st = 0; st < 2; ++st) {
    const f32x4 yr = (st == 0) ? acc00 : acc10;
    const f32x4 yi = (st == 0) ? acc01 : acc11;
    const float p0 = yr[0] * yr[0] + yi[0] * yi[0];
    const float p1 = yr[1] * yr[1] + yi[1] * yi[1];
    const float p2 = yr[2] * yr[2] + yi[2] * yi[2];
    const float p3 = yr[3] * yr[3] + yi[3] * yi[3];
    const float t  = p0 + p1 + p2 + p3;
    const float d5 = p0 + p1 - p2 - p3;   // wire5 <- i bit1 (reg bit1)
    const float d6 = p0 - p1 + p2 - p3;   // wire6 <- i bit0 (reg bit0)
    const float t16 = __shfl_xor(t, 16);
    const float a   = t + t16;
    const float b4  = (lane & 16) ? (t16 - t) : (t - t16);   // wire4 <- i bit2
    const float a32 = __shfl_xor(a, 32);
    const float T   = a + a32;
    const float D3  = (lane & 32) ? (a32 - a) : (a - a32);   // wire3 <- i bit3
    const float D4  = b4 + __shfl_xor(b4, 32);
    const float d5a = d5 + __shfl_xor(d5, 16);
    const float D5  = d5a + __shfl_xor(d5a, 32);
    const float d6a = d6 + __shfl_xor(d6, 16);
    const float D6  = d6a + __shfl_xor(d6a, 32);
    qv7[st][0] = sg0 ? -T : T;
    qv7[st][1] = sg1 ? -T : T;
    qv7[st][2] = sg2 ? -T : T;
    qv7[st][3] = D3; qv7[st][4] = D4; qv7[st][5] = D5; qv7[st][6] = D6;
  }
  __syncthreads();   // A-frag reads done everywhere; safe to alias qaP

  if (lane < 16) {
    #pragma unroll
    for (int st = 0; st < 2; ++st) {
      const int base = w * 288 + (st * 16 + lane) * 9;
      #pragma unroll
      for (int q = 0; q < 7; ++q) qaP[base + q] = qv7[st][q];
    }
  }
  __syncthreads();

  // ---- reduce over waves: thread (q = tid>>5, s = tid&31), q < 7 ----
  if (tid < 224) {
    const int q = tid >> 5, s = tid & 31;
    float acc = 0.f;
    #pragma unroll
    for (int wv = 0; wv < 8; ++wv) acc += qaP[wv * 288 + s * 9 + q];
    QA[s * 8 + q] = acc;
  }
  __syncthreads();

  // ---- MLP: thread (s, oo) computes logits oo and oo+11 for sample s ----
  if (tid < 352) {
    const int s  = tid / 11;
    const int oo = tid - s * 11;
    float qv[7];
    #pragma unroll
    for (int q = 0; q < 7; ++q) qv[q] = QA[s * 8 + q];
    float h[16];
    #pragma unroll
    for (int k = 0; k < 16; ++k) {
      float a2 = b1[k];
      #pragma unroll
      for (int q = 0; q < 7; ++q) a2 += W1[k * 7 + q] * qv[q];
      h[k] = fmaxf(a2, 0.f);
    }
    #pragma unroll
    for (int oi = 0; oi < 2; ++oi) {
      const int o = oo + oi * 11;
      float lg2 = b2[o];
      #pragma unroll
      for (int k = 0; k < 16; ++k) lg2 += W2[o * 16 + k] * h[k];
      out[(s0 + s) * 22 + o] = lg2;
    }
  }
}

extern "C" void kernel_launch(void* const* d_in, const int* in_sizes, int n_in,
                              void* d_out, int out_size, void* d_ws, size_t ws_size,
                              hipStream_t stream) {
  const float* x  = (const float*)d_in[0];
  const float* qw = (const float*)d_in[1];
  const float* W1 = (const float*)d_in[2];
  const float* b1 = (const float*)d_in[3];
  const float* W2 = (const float*)d_in[4];
  const float* b2 = (const float*)d_in[5];
  float* out = (float*)d_out;
  unsigned short* Bhi = (unsigned short*)d_ws;            // 64 KiB
  unsigned short* Blo = Bhi + 128 * 256;                  // 64 KiB

  const int B = in_sizes[0] / 7;

  build_unitary_k<<<32, 256, 0, stream>>>(qw, Bhi, Blo);

  vqc_mlp_k<<<B / 32, 512, 0, stream>>>(x, Bhi, Blo, W1, b1, W2, b2, out);
}

// Round 12
// 77.724 us; speedup vs baseline: 4.1426x; 1.0388x over previous
//
#include <hip/hip_runtime.h>
#include <math.h>

#define DIM 128

typedef __attribute__((ext_vector_type(8))) _Float16 f16x8;
typedef __attribute__((ext_vector_type(4))) float f32x4;

static __device__ __forceinline__ unsigned short f2h(float v) {
  _Float16 hv = (_Float16)v;           // RNE f32->f16
  unsigned short u;
  __builtin_memcpy(&u, &hv, 2);
  return u;
}

// ---------------- Kernel 1: build U in MFMA fragment layout (f16) ---------
// frag(ct,kt): elem (lane,e) = Bl[n][k], n = ct*16+(lane&15),
// k = kt*32+(lane>>4)*8+e, Bl[n][k] = (n<128)? Re U[n][k] : Im U[n-128][k].
__global__ __launch_bounds__(256) void build_unitary_k(
    const float* __restrict__ qw, unsigned short* __restrict__ Bf) {
  __shared__ float gm[35][8];
  const int tid = threadIdx.x;

  if (tid < 35) {
    const float phi = qw[tid * 3 + 0];
    const float th  = qw[tid * 3 + 1];
    const float om  = qw[tid * 3 + 2];
    float sh, ch; sincosf(0.5f * th, &sh, &ch);
    const float a = 0.5f * (phi + om);
    const float b = 0.5f * (phi - om);
    float sa, ca; sincosf(a, &sa, &ca);
    float sb, cb; sincosf(b, &sb, &cb);
    gm[tid][0] =  ca * ch;  gm[tid][1] = -sa * ch;
    gm[tid][2] = -cb * sh;  gm[tid][3] = -sb * sh;
    gm[tid][4] =  cb * sh;  gm[tid][5] = -sb * sh;
    gm[tid][6] =  ca * ch;  gm[tid][7] =  sa * ch;
  }
  __syncthreads();

  const int lane = tid & 63;
  const int k    = blockIdx.x * 4 + (tid >> 6);

  float rl = (k == lane)      ? 1.f : 0.f;
  float rh = (k == lane + 64) ? 1.f : 0.f;
  float il = 0.f, ih = 0.f;

  for (int l = 0; l < 5; ++l) {
    const int r = l % 6 + 1;
    for (int q = 0; q < 7; ++q) {
      const float* g = gm[l * 7 + q];
      const float g0 = g[0], g1 = g[1], g2 = g[2], g3 = g[3];
      const float g4 = g[4], g5 = g[5], g6 = g[6], g7 = g[7];
      if (q == 0) {
        const float nrl = g0 * rl - g1 * il + g2 * rh - g3 * ih;
        const float nil = g0 * il + g1 * rl + g2 * ih + g3 * rh;
        const float nrh = g4 * rl - g5 * il + g6 * rh - g7 * ih;
        const float nih = g4 * il + g5 * rl + g6 * ih + g7 * rh;
        rl = nrl; il = nil; rh = nrh; ih = nih;
      } else {
        const int m = 1 << (6 - q);
        const int bit = (lane & m) ? 1 : 0;
        const float prl = __shfl_xor(rl, m), pil = __shfl_xor(il, m);
        const float prh = __shfl_xor(rh, m), pih = __shfl_xor(ih, m);
        const float udr = bit ? g6 : g0, udi = bit ? g7 : g1;
        const float uor = bit ? g4 : g2, uoi = bit ? g5 : g3;
        const float nrl = udr * rl - udi * il + uor * prl - uoi * pil;
        const float nil = udr * il + udi * rl + uor * pil + uoi * prl;
        const float nrh = udr * rh - udi * ih + uor * prh - uoi * pih;
        const float nih = udr * ih + udi * rh + uor * pih + uoi * prh;
        rl = nrl; il = nil; rh = nrh; ih = nih;
      }
    }
    for (int q = 0; q < 7; ++q) {
      const int tg = (q + r) % 7;
      if (q == 0) {
        const int mt = 1 << (6 - tg);
        const float prh = __shfl_xor(rh, mt), pih = __shfl_xor(ih, mt);
        rh = prh; ih = pih;
      } else if (tg == 0) {
        const int mc = 1 << (6 - q);
        const bool cb = (lane & mc) != 0;
        const float trl = cb ? rh : rl, til = cb ? ih : il;
        const float trh = cb ? rl : rh, tih = cb ? il : ih;
        rl = trl; il = til; rh = trh; ih = tih;
      } else {
        const int mc = 1 << (6 - q), mt = 1 << (6 - tg);
        const bool cb = (lane & mc) != 0;
        const float prl = __shfl_xor(rl, mt), pil = __shfl_xor(il, mt);
        const float prh = __shfl_xor(rh, mt), pih = __shfl_xor(ih, mt);
        rl = cb ? prl : rl; il = cb ? pil : il;
        rh = cb ? prh : rh; ih = cb ? pih : ih;
      }
    }
  }

  const int kt = k >> 5, kl = (k >> 3) & 3, e = k & 7;
  {
    const float vals[4] = {rl, rh, il, ih};
    #pragma unroll
    for (int t = 0; t < 4; ++t) {
      const int n = lane + t * 64;
      const int off = (((n >> 4) * 4 + kt) * 64 + kl * 16 + (n & 15)) * 8 + e;
      Bf[off] = f2h(vals[t]);
    }
  }
}

// ---------------- Kernel 2: f16 MFMA GEMM + cheap epilogue + MLP ----------
// Block: 512 thr = 8 waves, 64 samples. Wave w: A = U row-tiles {w (Re), w+8 (Im)}
// from global; B = S f16 frags in LDS (4 sample-subtiles). D: col = sample,
// row = u-sub-index. Single-term f16 product (err ~1e-3 << 9.6e-3 threshold).
__global__ __launch_bounds__(512, 4) void vqc_mlp_k(
    const float* __restrict__ x, const unsigned short* __restrict__ Bf,
    const float* __restrict__ W1, const float* __restrict__ b1,
    const float* __restrict__ W2, const float* __restrict__ b2,
    float* __restrict__ out) {
  __shared__ float smem[5120];                         // 20 KB
  unsigned short* Ahf = (unsigned short*)smem;         // 64*136 ushorts = 17408 B
  float* qaP = smem;                                   // alias post-MFMA: [8][64][9]
  float* QA  = smem + 4608;                            // [64][8]

  const int tid  = threadIdx.x;
  const int lane = tid & 63;
  const int w    = tid >> 6;
  const int s0   = blockIdx.x * 64;

  // ---- S tile: product state -> f16 fragments (8 thr/sample, 16 k each) ----
  {
    const int sam = tid >> 3;       // 0..63
    const int ko  = tid & 7;        // k = ko*16 + j
    const float* xp = x + (s0 + sam) * 7;
    float cq[7], sq[7];
    #pragma unroll
    for (int q = 0; q < 7; ++q) __sincosf(0.5f * xp[q], &sq[q], &cq[q]);
    // k bits 6..4 = ko bits 2..0 (wires 0..2); k bits 3..0 = j (wires 3..6)
    float sv[16];
    sv[0] = ((ko & 4) ? sq[0] : cq[0]) * ((ko & 2) ? sq[1] : cq[1]) *
            ((ko & 1) ? sq[2] : cq[2]);
    #pragma unroll
    for (int q = 3; q < 7; ++q) {
      const int cnt = 1 << (q - 3);
      #pragma unroll
      for (int t2 = cnt - 1; t2 >= 0; --t2) {
        const float v = sv[t2];
        sv[2 * t2 + 1] = v * sq[q];
        sv[2 * t2]     = v * cq[q];
      }
    }
    f16x8 h8a, h8b;
    #pragma unroll
    for (int e = 0; e < 8; ++e) {
      h8a[e] = (_Float16)sv[e];
      h8b[e] = (_Float16)sv[8 + e];
    }
    *(f16x8*)&Ahf[sam * 136 + ko * 16]     = h8a;
    *(f16x8*)&Ahf[sam * 136 + ko * 16 + 8] = h8b;
  }
  __syncthreads();

  // ---- main loop: D[u-idx][sample]; 1-term f16, K=128, 4 sample-subtiles ----
  const f16x8* __restrict__ Bf8 = (const f16x8*)Bf;
  const int boff0 = (w * 4) * 64 + lane;          // ct0 = w      (Re rows)
  const int boff1 = ((w + 8) * 4) * 64 + lane;    // ct1 = w + 8  (Im rows)
  f32x4 accR[4], accI[4];
  #pragma unroll
  for (int st = 0; st < 4; ++st) {
    accR[st] = (f32x4){0.f, 0.f, 0.f, 0.f};
    accI[st] = (f32x4){0.f, 0.f, 0.f, 0.f};
  }
  const int kloff = (lane >> 4) * 8;
  const int csub  = lane & 15;
  #pragma unroll
  for (int kt = 0; kt < 4; ++kt) {
    const f16x8 bh0 = Bf8[boff0 + kt * 64];
    const f16x8 bh1 = Bf8[boff1 + kt * 64];
    const int ko2 = kt * 32 + kloff;
    #pragma unroll
    for (int st = 0; st < 4; ++st) {
      const f16x8 ah = *(const f16x8*)&Ahf[(st * 16 + csub) * 136 + ko2];
      accR[st] = __builtin_amdgcn_mfma_f32_16x16x32_f16(bh0, ah, accR[st], 0, 0, 0);
      accI[st] = __builtin_amdgcn_mfma_f32_16x16x32_f16(bh1, ah, accI[st], 0, 0, 0);
    }
  }

  // ---- epilogue: i = w*16 + (lane>>4)*4 + r. wires 5,6 <- r bits (in-lane);
  // wires 3,4 <- lane bits 5,4 (2 shfl stages); wires 0-2 <- w bits (signs) ----
  const int sg0 = (w >> 2) & 1, sg1 = (w >> 1) & 1, sg2 = w & 1;
  float qv7[4][7];
  #pragma unroll
  for (int st = 0; st < 4; ++st) {
    const f32x4 yr = accR[st];
    const f32x4 yi = accI[st];
    const float p0 = yr[0] * yr[0] + yi[0] * yi[0];
    const float p1 = yr[1] * yr[1] + yi[1] * yi[1];
    const float p2 = yr[2] * yr[2] + yi[2] * yi[2];
    const float p3 = yr[3] * yr[3] + yi[3] * yi[3];
    const float t  = p0 + p1 + p2 + p3;
    const float d5 = p0 + p1 - p2 - p3;   // wire5 <- i bit1
    const float d6 = p0 - p1 + p2 - p3;   // wire6 <- i bit0
    const float t16 = __shfl_xor(t, 16);
    const float a   = t + t16;
    const float b4  = (lane & 16) ? (t16 - t) : (t - t16);   // wire4 <- i bit2
    const float a32 = __shfl_xor(a, 32);
    const float T   = a + a32;
    const float D3  = (lane & 32) ? (a32 - a) : (a - a32);   // wire3 <- i bit3
    const float D4  = b4 + __shfl_xor(b4, 32);
    const float d5a = d5 + __shfl_xor(d5, 16);
    const float D5  = d5a + __shfl_xor(d5a, 32);
    const float d6a = d6 + __shfl_xor(d6, 16);
    const float D6  = d6a + __shfl_xor(d6a, 32);
    qv7[st][0] = sg0 ? -T : T;
    qv7[st][1] = sg1 ? -T : T;
    qv7[st][2] = sg2 ? -T : T;
    qv7[st][3] = D3; qv7[st][4] = D4; qv7[st][5] = D5; qv7[st][6] = D6;
  }
  __syncthreads();   // A-frag reads done; safe to alias qaP

  if (lane < 16) {
    #pragma unroll
    for (int st = 0; st < 4; ++st) {
      const int base = w * 576 + (st * 16 + lane) * 9;
      #pragma unroll
      for (int q = 0; q < 7; ++q) qaP[base + q] = qv7[st][q];
    }
  }
  __syncthreads();

  // ---- reduce over waves: thread (q = tid>>6, s = tid&63), q < 7 ----
  if (tid < 448) {
    const int q = tid >> 6, s = tid & 63;
    float acc = 0.f;
    #pragma unroll
    for (int wv = 0; wv < 8; ++wv) acc += qaP[wv * 576 + s * 9 + q];
    QA[s * 8 + q] = acc;
  }
  __syncthreads();

  // ---- MLP: thread (s = tid>>3, t8 = tid&7) emits logits t8, t8+8, t8+16 ----
  {
    const int s  = tid >> 3;
    const int t8 = tid & 7;
    float qv[7];
    #pragma unroll
    for (int q = 0; q < 7; ++q) qv[q] = QA[s * 8 + q];
    float h[16];
    #pragma unroll
    for (int k = 0; k < 16; ++k) {
      float a2 = b1[k];
      #pragma unroll
      for (int q = 0; q < 7; ++q) a2 += W1[k * 7 + q] * qv[q];
      h[k] = fmaxf(a2, 0.f);
    }
    #pragma unroll
    for (int oi = 0; oi < 3; ++oi) {
      const int o = t8 + oi * 8;
      if (o < 22) {
        float lg2 = b2[o];
        #pragma unroll
        for (int k = 0; k < 16; ++k) lg2 += W2[o * 16 + k] * h[k];
        out[(s0 + s) * 22 + o] = lg2;
      }
    }
  }
}

extern "C" void kernel_launch(void* const* d_in, const int* in_sizes, int n_in,
                              void* d_out, int out_size, void* d_ws, size_t ws_size,
                              hipStream_t stream) {
  const float* x  = (const float*)d_in[0];
  const float* qw = (const float*)d_in[1];
  const float* W1 = (const float*)d_in[2];
  const float* b1 = (const float*)d_in[3];
  const float* W2 = (const float*)d_in[4];
  const float* b2 = (const float*)d_in[5];
  float* out = (float*)d_out;
  unsigned short* Bf = (unsigned short*)d_ws;            // 64 KiB f16 U-frags

  const int B = in_sizes[0] / 7;

  build_unitary_k<<<32, 256, 0, stream>>>(qw, Bf);

  vqc_mlp_k<<<B / 64, 512, 0, stream>>>(x, Bf, W1, b1, W2, b2, out);
}